// Round 10
// baseline (454.429 us; speedup 1.0000x reference)
//
#include <hip/hip_runtime.h>
#include <stdint.h>

#define BS 8
#define HH 192
#define WW 192
#define HW (HH*WW)     /* 36864 */
#define KK 16
#define KCAP 256       /* u64 survivor keys per (wave,query) */
#define PAD 1e-4f      /* covers approx(fma) vs exact(rn) sim error (~2e-6) */

typedef unsigned long long u64;

// ---------- helpers ----------

__device__ __forceinline__ uint32_t fkey(float f) {
    uint32_t u = __float_as_uint(f);
    uint32_t mask = (uint32_t)((int32_t)u >> 31) | 0x80000000u;
    return u ^ mask;
}
__device__ __forceinline__ float inv_fkey(uint32_t v) {
    uint32_t u = (v & 0x80000000u) ? (v ^ 0x80000000u) : ~v;
    return __uint_as_float(u);
}

__device__ __forceinline__ u64 umin64(u64 a, u64 b) { return a < b ? a : b; }

__device__ __forceinline__ u64 wave_min_u64(u64 v) {
    #pragma unroll
    for (int off = 32; off >= 1; off >>= 1) {
        uint32_t lo = (uint32_t)v, hi = (uint32_t)(v >> 32);
        lo = __shfl_xor(lo, off, 64);
        hi = __shfl_xor(hi, off, 64);
        u64 o = ((u64)hi << 32) | lo;
        v = umin64(v, o);
    }
    return v;
}

__device__ __forceinline__ float wave_min_f32(float v) {
    #pragma unroll
    for (int off = 32; off >= 1; off >>= 1)
        v = fminf(v, __shfl_xor(v, off, 64));
    return v;
}

__device__ __forceinline__ float exact_rsq(float a, float b, float c) {
    return __fadd_rn(__fadd_rn(__fmul_rn(a, a), __fmul_rn(b, b)), __fmul_rn(c, c));
}
__device__ __forceinline__ float exact_sim(float c0, float c1, float c2, float rsq, float4 pq) {
    float cr = __fadd_rn(__fadd_rn(__fmul_rn(c0, pq.x), __fmul_rn(c1, pq.y)), __fmul_rn(c2, pq.z));
    return __fadd_rn(__fsub_rn(rsq, __fmul_rn(2.0f, cr)), pq.w);
}

// tau: binary search (approx-key domain) for bound with >=16 px <= tau per wave.
// lo seed <= answer; hi seed sound (min-of-per-lane-maxima lane has 16 px <= hi).
__device__ __forceinline__ uint32_t tau_search(float mn, float mx) {
    uint32_t kmin = fkey(mn);
    uint32_t lo = fkey(wave_min_f32(mn));
    uint32_t hi = fkey(wave_min_f32(mx));
    #pragma unroll 1
    for (int t = 0; t < 20; ++t) {
        uint32_t mid = lo + ((hi - lo) >> 1);
        int c = __popcll(__ballot(kmin <= mid));
        if (c >= KK) hi = mid; else lo = mid + 1;
    }
    return hi;
}

// per-lane <=4 keys from kw[0..scnt), sort-4, 16-round wave min-pop -> mrow sorted
__device__ __forceinline__ void select_top16(const u64* kw, int scnt, u64* mrow, int lane) {
    u64 k0 = (lane       < scnt) ? kw[lane]       : ~0ull;
    u64 k1 = (lane + 64  < scnt) ? kw[lane + 64]  : ~0ull;
    u64 k2 = (lane + 128 < scnt) ? kw[lane + 128] : ~0ull;
    u64 k3 = (lane + 192 < scnt) ? kw[lane + 192] : ~0ull;
    #define CSWAP(A, B) { u64 mn = umin64(A, B); u64 mx = (A < B) ? B : A; A = mn; B = mx; }
    CSWAP(k0, k1) CSWAP(k2, k3) CSWAP(k0, k2) CSWAP(k1, k3) CSWAP(k1, k2)
    #undef CSWAP
    #pragma unroll 1
    for (int r = 0; r < KK; ++r) {
        u64 m = wave_min_u64(k0);
        if (lane == 0) mrow[r] = m;
        if (k0 == m && m != ~0ull) { k0 = k1; k1 = k2; k2 = k3; k3 = ~0ull; }
    }
}

// ---------- single fused kernel: block = 2 queries of image b; 4 waves split image ----------
__global__ __launch_bounds__(256, 4) void topk_kernel(const float* __restrict__ pred,
                                                      const float* __restrict__ ref,
                                                      double* __restrict__ dacc,
                                                      uint32_t* __restrict__ dcnt,
                                                      float* __restrict__ out) {
    __shared__ u64 kbuf[4][2][KCAP];   // 16 KB survivor keys
    __shared__ u64 mbuf[2][64];        // per-query 4x16 sorted candidates
    __shared__ uint32_t wtk[2][4];
    __shared__ float4 spool[2];
    __shared__ float sterm[2];

    const int lane = threadIdx.x & 63;
    const int wid  = threadIdx.x >> 6;
    const int b  = blockIdx.x & 7;     // XCD swizzle: image -> one XCD's L2
    const int qp = blockIdx.x >> 3;    // 0..127 -> queries l = 2qp, 2qp+1

    // ---- pooled for the 2 queries (threads 0,1) ----
    if (threadIdx.x < 2) {
        int l = qp * 2 + threadIdx.x;
        int i = l * BS + b;            // scrambled flat grid row
        int b2 = i >> 8, l2 = i & 255;
        const float* pr = pred + ((b2 * 256 + l2) * 8);
        float x = pr[0], y = pr[1];
        float fx = rintf(__fsub_rn(__fmul_rn(x, 192.0f), 0.5f));
        float fy = rintf(__fsub_rn(__fmul_rn(y, 192.0f), 0.5f));
        int ix = (int)fx, iy = (int)fy;
        int inb = (ix >= 0 && ix < WW && iy >= 0 && iy < HH) ? 1 : 0;
        int ixc = min(max(ix, 0), WW - 1);
        int iyc = min(max(iy, 0), HH - 1);
        float m = (float)inb;
        const float* img = ref + b * 3 * HW + iyc * WW + ixc;
        float p0 = __fmul_rn(img[0], m);
        float p1 = __fmul_rn(img[HW], m);
        float p2 = __fmul_rn(img[2 * HW], m);
        float psq = __fadd_rn(__fadd_rn(__fmul_rn(p0, p0), __fmul_rn(p1, p1)), __fmul_rn(p2, p2));
        spool[threadIdx.x] = make_float4(p0, p1, p2, psq);
    }
    __syncthreads();
    const float4 pq0 = spool[0];
    const float4 pq1 = spool[1];

    const float*  imgb = ref + (size_t)b * 3 * HW;
    const float4* p0g  = (const float4*)imgb;
    const int wq4 = wid * 2304;        // wave's quarter (float4 units)

    float4 Pa0, Pa1, Pa2, Pb0, Pb1, Pb2;   // pipeline buffer P: 2 sites x 3 planes
    float4 Qa0, Qa1, Qa2, Qb0, Qb1, Qb2;   // pipeline buffer Q

    #define LOADB(N, J)                                                     \
    {   int v0 = wq4 + (2 * (J)) * 64 + lane;                               \
        N##a0 = p0g[v0];      N##a1 = p0g[v0 + 9216];  N##a2 = p0g[v0 + 18432]; \
        N##b0 = p0g[v0 + 64]; N##b1 = p0g[v0 + 9280];  N##b2 = p0g[v0 + 18496]; }

    // ---- warm pass: steps 0,1 (sites 0..3), track per-lane min/max per query ----
    LOADB(P, 0) LOADB(Q, 1)
    float mn0 = 1e30f, mx0 = -1e30f, mn1 = 1e30f, mx1 = -1e30f;
    #define WPX(c0v, c1v, c2v, comp)                                                        \
    {   float rsf = fmaf(c2v.comp, c2v.comp, fmaf(c1v.comp, c1v.comp, c0v.comp*c0v.comp));  \
        float cr0 = fmaf(c2v.comp, pq0.z, fmaf(c1v.comp, pq0.y, c0v.comp*pq0.x));           \
        float cr1 = fmaf(c2v.comp, pq1.z, fmaf(c1v.comp, pq1.y, c0v.comp*pq1.x));           \
        float s0 = fmaf(-2.0f, cr0, rsf) + pq0.w;                                           \
        float s1 = fmaf(-2.0f, cr1, rsf) + pq1.w;                                           \
        mn0 = fminf(mn0, s0); mx0 = fmaxf(mx0, s0);                                         \
        mn1 = fminf(mn1, s1); mx1 = fmaxf(mx1, s1); }
    #define WSITE(c0v, c1v, c2v) WPX(c0v,c1v,c2v,x) WPX(c0v,c1v,c2v,y) WPX(c0v,c1v,c2v,z) WPX(c0v,c1v,c2v,w)
    WSITE(Pa0, Pa1, Pa2) WSITE(Pb0, Pb1, Pb2) WSITE(Qa0, Qa1, Qa2) WSITE(Qb0, Qb1, Qb2)
    #undef WSITE
    #undef WPX

    wtk[0][wid] = tau_search(mn0, mx0);
    wtk[1][wid] = tau_search(mn1, mx1);
    __syncthreads();
    const uint32_t tk0 = min(min(wtk[0][0], wtk[0][1]), min(wtk[0][2], wtk[0][3]));
    const uint32_t tk1 = min(min(wtk[1][0], wtk[1][1]), min(wtk[1][2], wtk[1][3]));
    const float tauf0 = inv_fkey(tk0) + 2.0f * PAD;
    const float tauf1 = inv_fkey(tk1) + 2.0f * PAD;
    const float h0 = (pq0.w - tauf0) * 0.5f;   // filter: pass <=> crf >= rsf*0.5 + h
    const float h1 = (pq1.w - tauf1) * 0.5f;

    // ---- pipelined branch-free scan: 18 steps x 2 sites, masks in registers ----
    uint32_t U0 = 0, U1 = 0, U2 = 0, U3 = 0, U4 = 0;   // q0: word w = sites 8w..8w+7
    uint32_t V0 = 0, V1 = 0, V2 = 0, V3 = 0, V4 = 0;   // q1

    #define PXB(c0v, c1v, c2v, comp, bit)                                                   \
    {   float rsf = fmaf(c2v.comp, c2v.comp, fmaf(c1v.comp, c1v.comp, c0v.comp*c0v.comp));  \
        float cr0 = fmaf(c2v.comp, pq0.z, fmaf(c1v.comp, pq0.y, c0v.comp*pq0.x));           \
        float cr1 = fmaf(c2v.comp, pq1.z, fmaf(c1v.comp, pq1.y, c0v.comp*pq1.x));           \
        if (cr0 >= fmaf(rsf, 0.5f, h0)) nb0 |= (bit);                                       \
        if (cr1 >= fmaf(rsf, 0.5f, h1)) nb1 |= (bit); }
    #define SITEB(c0v, c1v, c2v, BO)                                        \
        PXB(c0v,c1v,c2v,x, 1u<<(BO))   PXB(c0v,c1v,c2v,y, 1u<<((BO)+1))     \
        PXB(c0v,c1v,c2v,z, 1u<<((BO)+2)) PXB(c0v,c1v,c2v,w, 1u<<((BO)+3))
    #define STEPB(N, MW, NW, SH)                                            \
    {   uint32_t nb0 = 0, nb1 = 0;                                          \
        SITEB(N##a0, N##a1, N##a2, 0)                                       \
        SITEB(N##b0, N##b1, N##b2, 4)                                       \
        MW |= nb0 << (SH); NW |= nb1 << (SH); }

    LOADB(P, 0) LOADB(Q, 1)                     // warm sites re-read (L1/L2 hot)
    STEPB(P, U0, V0,  0)  LOADB(P, 2)
    STEPB(Q, U0, V0,  8)  LOADB(Q, 3)
    STEPB(P, U0, V0, 16)  LOADB(P, 4)
    STEPB(Q, U0, V0, 24)  LOADB(Q, 5)
    STEPB(P, U1, V1,  0)  LOADB(P, 6)
    STEPB(Q, U1, V1,  8)  LOADB(Q, 7)
    STEPB(P, U1, V1, 16)  LOADB(P, 8)
    STEPB(Q, U1, V1, 24)  LOADB(Q, 9)
    STEPB(P, U2, V2,  0)  LOADB(P, 10)
    STEPB(Q, U2, V2,  8)  LOADB(Q, 11)
    STEPB(P, U2, V2, 16)  LOADB(P, 12)
    STEPB(Q, U2, V2, 24)  LOADB(Q, 13)
    STEPB(P, U3, V3,  0)  LOADB(P, 14)
    STEPB(Q, U3, V3,  8)  LOADB(Q, 15)
    STEPB(P, U3, V3, 16)  LOADB(P, 16)
    STEPB(Q, U3, V3, 24)  LOADB(Q, 17)
    STEPB(P, U4, V4,  0)
    STEPB(Q, U4, V4,  8)
    #undef STEPB
    #undef SITEB
    #undef PXB
    #undef LOADB

    // ---- per-query: prefix offsets, gather survivors, exact keys -> LDS ----
    #define PROC(W, WIDX, KW, OFFV, PQ)                                         \
    {   uint32_t wv = (W);                                                      \
        while (wv) {                                                            \
            int i = __ffs(wv) - 1; wv &= wv - 1;                                \
            int site = (WIDX) * 8 + (i >> 2);                                   \
            uint32_t p = (uint32_t)((wq4 + site * 64 + lane) * 4 + (i & 3));    \
            float c0 = imgb[p], c1 = imgb[p + HW], c2 = imgb[p + 2 * HW];       \
            float rs = exact_rsq(c0, c1, c2);                                   \
            float s  = exact_sim(c0, c1, c2, rs, PQ);                           \
            if (OFFV < KCAP) KW[OFFV] = ((u64)fkey(s) << 32) | p;               \
            OFFV++;                                                             \
        } }
    #define PREFIX(CNT, OFFV, TOT)                                              \
    {   int pref = (CNT);                                                       \
        _Pragma("unroll")                                                       \
        for (int i = 1; i < 64; i <<= 1) {                                      \
            int t = __shfl_up(pref, i, 64);                                     \
            if (lane >= i) pref += t;                                           \
        }                                                                       \
        TOT = __shfl(pref, 63, 64);                                             \
        OFFV = pref - (CNT); }

    int scnt0, scnt1;
    {
        int cnt = __popc(U0) + __popc(U1) + __popc(U2) + __popc(U3) + __popc(U4);
        int off;
        PREFIX(cnt, off, scnt0)
        u64* kw = kbuf[wid][0];
        PROC(U0, 0, kw, off, pq0) PROC(U1, 1, kw, off, pq0) PROC(U2, 2, kw, off, pq0)
        PROC(U3, 3, kw, off, pq0) PROC(U4, 4, kw, off, pq0)
        if (scnt0 > KCAP) scnt0 = KCAP;
    }
    {
        int cnt = __popc(V0) + __popc(V1) + __popc(V2) + __popc(V3) + __popc(V4);
        int off;
        PREFIX(cnt, off, scnt1)
        u64* kw = kbuf[wid][1];
        PROC(V0, 0, kw, off, pq1) PROC(V1, 1, kw, off, pq1) PROC(V2, 2, kw, off, pq1)
        PROC(V3, 3, kw, off, pq1) PROC(V4, 4, kw, off, pq1)
        if (scnt1 > KCAP) scnt1 = KCAP;
    }
    #undef PREFIX
    #undef PROC

    // ---- per-wave sorted top-16 per query -> mbuf ----
    select_top16(kbuf[wid][0], scnt0, &mbuf[0][wid * KK], lane);
    select_top16(kbuf[wid][1], scnt1, &mbuf[1][wid * KK], lane);
    __syncthreads();

    // ---- waves 0,1: rank-merge 64 candidates of q0,q1; argmin vs row l+1 ----
    if (wid < 2) {
        const int q = wid;
        u64 v = mbuf[q][lane];         // real keys distinct; ~0 sentinels rank last
        int rank = 0;
        #pragma unroll 1
        for (int m = 0; m < 64; ++m) {
            uint32_t lo = __shfl((uint32_t)v, m, 64);
            uint32_t hi = __shfl((uint32_t)(v >> 32), m, 64);
            u64 o = ((u64)hi << 32) | lo;
            rank += (o < v) ? 1 : 0;
        }
        const int lq = qp * 2 + q;
        const int row = lq + 1;
        if (row <= 255) {
            bool valid = (v != ~0ull) && (rank < KK);   // >=16 real survivors guaranteed
            float px1 = pred[(size_t)(b * 256 + row) * 8 + 0];
            float py1 = pred[(size_t)(b * 256 + row) * 8 + 1];
            float tx = 0.0f, ty = 0.0f;
            u64 dkey = ~0ull;
            if (valid) {
                uint32_t idx = (uint32_t)v;
                tx = (float)(idx % WW) / 192.0f;
                ty = (float)(idx / WW) / 192.0f;
                float dx = __fsub_rn(px1, tx);
                float dy = __fsub_rn(py1, ty);
                float d = __fadd_rn(__fmul_rn(dx, dx), __fmul_rn(dy, dy));
                dkey = ((u64)__float_as_uint(d) << 32) | (uint32_t)rank;  // tie -> low rank
            }
            u64 wmin = wave_min_u64(dkey);
            if (dkey == wmin && valid) {
                float ex = __fsub_rn(px1, tx);
                float ey = __fsub_rn(py1, ty);
                sterm[q] = __fadd_rn(__fmul_rn(ex, ex), __fmul_rn(ey, ey));
            }
        } else {
            if (lane == 0) sterm[q] = 0.0f;   // l=255's targets feed excluded row 0
        }
    }
    __syncthreads();

    // ---- thread 0: accumulate block's 2 terms; last block finalizes mean ----
    if (threadIdx.x == 0) {
        atomicAdd(dacc, (double)sterm[0] + (double)sterm[1]);
        __threadfence();
        uint32_t old = atomicAdd(dcnt, 1u);
        if (old == 1023u) {
            double s = atomicAdd(dacc, 0.0);
            out[0] = (float)(s / 2040.0);
        }
    }
}

// ---------- launch ----------
extern "C" void kernel_launch(void* const* d_in, const int* in_sizes, int n_in,
                              void* d_out, int out_size, void* d_ws, size_t ws_size,
                              hipStream_t stream) {
    const float* pred = (const float*)d_in[0];   // (8,256,8) f32
    const float* ref  = (const float*)d_in[1];   // (8,3,192,192) f32
    float* out = (float*)d_out;

    double*   dacc = (double*)d_ws;              // 8 B accumulator
    uint32_t* dcnt = (uint32_t*)((char*)d_ws + 8);

    hipMemsetAsync(d_ws, 0, 16, stream);
    topk_kernel<<<1024, 256, 0, stream>>>(pred, ref, dacc, dcnt, out);
}